// Round 1
// baseline (334.834 us; speedup 1.0000x reference)
//
#include <hip/hip_runtime.h>

#define TX 32
#define TY 32
#define RAD 5
#define HXS (TX + 2*RAD)   // 42 (halo width)
#define HYS (TY + 2*RAD)   // 42 (halo height)

// Gaussian weights for K=11, sigma=1.5 (precomputed, normalized; sum=1 to ~1e-7)
#define KW0 0.00102838f
#define KW1 0.00759875f
#define KW2 0.03600077f
#define KW3 0.10936069f
#define KW4 0.21300554f
#define KW5 0.26601172f

__global__ __launch_bounds__(256) void ssim_fused_kernel(
    const float* __restrict__ xlog, const float* __restrict__ yin,
    float* __restrict__ accum, int Himg, int Wimg)
{
    const float kw[11] = {KW0, KW1, KW2, KW3, KW4, KW5, KW4, KW3, KW2, KW1, KW0};

    __shared__ float xs[HYS][HXS + 2];      // 42 x 44
    __shared__ float ys[HYS][HXS + 2];      // 42 x 44
    __shared__ float hbuf[5][HYS][TX + 1];  // 5 x 42 x 33

    const int tid  = threadIdx.x;
    const int img  = blockIdx.z;
    const long long base = (long long)img * Himg * Wimg;
    const int row0 = blockIdx.y * TY - RAD;
    const int col0 = blockIdx.x * TX - RAD;

    // ---- Stage 1: global -> LDS (sigmoid on x; zero-pad OOB) ----
    for (int i = tid; i < HYS * HXS; i += 256) {
        int r = i / HXS;
        int c = i - r * HXS;
        int gr = row0 + r, gc = col0 + c;
        float xv = 0.f, yv = 0.f;
        if (gr >= 0 && gr < Himg && gc >= 0 && gc < Wimg) {
            long long idx = base + (long long)gr * Wimg + gc;
            float lx = xlog[idx];
            xv = 1.0f / (1.0f + __expf(-lx));
            yv = yin[idx];
        }
        xs[r][c] = xv;
        ys[r][c] = yv;
    }
    __syncthreads();

    // ---- Stage 2: horizontal 11-tap blur of {x, y, xx, yy, xy} ----
    for (int i = tid; i < HYS * TX; i += 256) {
        int r = i >> 5;          // TX == 32
        int c = i & (TX - 1);
        float sx = 0.f, sy = 0.f, sxx = 0.f, syy = 0.f, sxy = 0.f;
        #pragma unroll
        for (int j = 0; j < 11; ++j) {
            float w  = kw[j];
            float xv = xs[r][c + j];
            float yv = ys[r][c + j];
            sx  += w * xv;
            sy  += w * yv;
            sxx += w * xv * xv;
            syy += w * yv * yv;
            sxy += w * xv * yv;
        }
        hbuf[0][r][c] = sx;
        hbuf[1][r][c] = sy;
        hbuf[2][r][c] = sxx;
        hbuf[3][r][c] = syy;
        hbuf[4][r][c] = sxy;
    }
    __syncthreads();

    // ---- Stage 3: vertical 11-tap blur + SSIM per pixel ----
    float local = 0.f;
    const int c  = tid & (TX - 1);
    const int r0 = tid >> 5;     // 0..7
    #pragma unroll
    for (int k = 0; k < TY / 8; ++k) {
        int r = r0 + k * 8;      // output row in tile
        float ux = 0.f, uy = 0.f, uxx = 0.f, uyy = 0.f, uxy = 0.f;
        #pragma unroll
        for (int j = 0; j < 11; ++j) {
            float w = kw[j];
            ux  += w * hbuf[0][r + j][c];
            uy  += w * hbuf[1][r + j][c];
            uxx += w * hbuf[2][r + j][c];
            uyy += w * hbuf[3][r + j][c];
            uxy += w * hbuf[4][r + j][c];
        }
        float vx  = uxx - ux * ux;
        float vy  = uyy - uy * uy;
        float vxy = uxy - ux * uy;
        const float c1 = 1e-4f;   // 0.01^2
        const float c2 = 9e-4f;   // 0.03^2
        float num = (2.f * ux * uy + c1) * (2.f * vxy + c2);
        float den = (ux * ux + uy * uy + c1) * (vx + vy + c2);
        local += num / (den + 1e-12f);
    }

    // ---- Stage 4: block reduction -> one atomicAdd ----
    #pragma unroll
    for (int off = 32; off > 0; off >>= 1)
        local += __shfl_down(local, off, 64);
    __shared__ float wsum[4];
    int wave = tid >> 6;
    if ((tid & 63) == 0) wsum[wave] = local;
    __syncthreads();
    if (tid == 0) {
        float s = wsum[0] + wsum[1] + wsum[2] + wsum[3];
        atomicAdd(accum, s);
    }
}

__global__ void ssim_finalize_kernel(const float* __restrict__ accum,
                                     float* __restrict__ out, float invN)
{
    out[0] = 1.0f - accum[0] * invN;
}

extern "C" void kernel_launch(void* const* d_in, const int* in_sizes, int n_in,
                              void* d_out, int out_size, void* d_ws, size_t ws_size,
                              hipStream_t stream) {
    const float* xlog = (const float*)d_in[0];
    const float* yin  = (const float*)d_in[1];
    float* out = (float*)d_out;
    float* acc = (float*)d_ws;

    const int Himg = 512, Wimg = 512;
    const int B = in_sizes[0] / (Himg * Wimg);   // 64

    // d_ws is re-poisoned to 0xAA before every timed call: zero the accumulator.
    hipMemsetAsync(acc, 0, sizeof(float), stream);

    dim3 grid(Wimg / TX, Himg / TY, B);
    ssim_fused_kernel<<<grid, 256, 0, stream>>>(xlog, yin, acc, Himg, Wimg);

    float invN = 1.0f / ((float)B * Himg * Wimg);
    ssim_finalize_kernel<<<1, 1, 0, stream>>>(acc, out, invN);
}